// Round 8
// baseline (12211.044 us; speedup 1.0000x reference)
//
#include <hip/hip_runtime.h>
#include <math.h>

// DenseLSTMForecast: B=256, T=1024, H=128, FUTURE=32.
// R8 = R7 (full-fp32 recurrence-decoupled pipeline, PASSED 8.1ms) with the
// dot kernel restructured. R7 counters: VALUBusy 36%, conflicts 0, step time
// 7.7us == 2048 broadcast ds_read_b128 x ~9cyc per CU-step -> LDS-broadcast
// -issue bound (broadcast charges full 1KB/inst bandwidth even for 16 unique
// bytes). R8 moves the h-broadcast off the LDS pipe: distributed ds_read_b32
// (lane l holds h[l], 16 LDS insts/thread/step vs 256), then per-k
// v_readlane_b32 -> SGPR -> v_fmac_f32 acc, s_h, v_w (SGPR src0 is free).
// VALU/wave/step: 1024 fmac + 1024 readlane ~= 2048 -> ~3.5us/step predicted.
// Summation order identical to R7 -> absmax should match 4.88e-4.
//
// Structure (unchanged from R7): 32 row-groups (8 rows) x 7 stages:
//   s0 c1-core, s1 c2-helper, s2 c2-core, s3 c3-helperA, s4 c3-helperB,
//   s5 c3-core, s6 head. 224 WGs x 512 thr; group g's stages share an XCD.
// Monotonic per-stage flags, tid0-cached; payload via relaxed agent atomics.

#define TSEQ 1024
#define HH   128
#define TT   1056

// ---- ws dword offsets ----
#define PLANES   0                 // 6 planes x [128 k][512 g] fp32
#define SCAL     393216            // xw1,xw2,xw3,bs1,bs2,bs3 (512 each)
#define WLIN     396288            // Wlin[0..384], [385]=b_lin, pad 512
#define XT       396800            // x transposed [1024][256]
#define RH1      658944            // h rings: [16][256][128] fp32
#define RH2      1183232
#define RH3      1707520
#define RO       2231808           // o ring [16][256] fp32
#define RP2      2235904           // partial rings: [8][256][512] fp32
#define RP3A     3284480
#define RP3B     4333056
#define FLAGS    5381632           // 224 x 32-dword lines
#define PREP_TOT 666112            // 658944 + 7168 (flags zeroing)

#define RH1_64 (RH1/2)
#define RH2_64 (RH2/2)
#define RH3_64 (RH3/2)

typedef unsigned long long u64;

__device__ __forceinline__ float sigmoidf_(float v) {
  return 1.0f / (1.0f + expf(-v));
}

__device__ __forceinline__ void wait_c(unsigned* p, unsigned tgt, unsigned& cached) {
  if (cached >= tgt) return;
  unsigned v = __hip_atomic_load(p, __ATOMIC_ACQUIRE, __HIP_MEMORY_SCOPE_AGENT);
  while (v < tgt) {
    __builtin_amdgcn_s_sleep(1);
    v = __hip_atomic_load(p, __ATOMIC_ACQUIRE, __HIP_MEMORY_SCOPE_AGENT);
  }
  cached = v;
}

// ---------------------------------------------------------------------------
__global__ void prep_kernel(const float* __restrict__ x,
                            const float* __restrict__ Wih1, const float* __restrict__ Whh1,
                            const float* __restrict__ bih1, const float* __restrict__ bhh1,
                            const float* __restrict__ Wih2, const float* __restrict__ Whh2,
                            const float* __restrict__ bih2, const float* __restrict__ bhh2,
                            const float* __restrict__ Wih3, const float* __restrict__ Whh3,
                            const float* __restrict__ bih3, const float* __restrict__ bhh3,
                            const float* __restrict__ Wlin, const float* __restrict__ blin,
                            float* __restrict__ ws) {
  int idx = blockIdx.x * 256 + threadIdx.x;
  if (idx < SCAL) {
    int p = idx >> 16;            // plane
    int rem = idx & 65535;
    int k = rem >> 9, g = rem & 511;
    float v;
    switch (p) {
      case 0:  v = Whh1[g * HH + k];         break;
      case 1:  v = Wih2[g * 129 + 1 + k];    break;
      case 2:  v = Whh2[g * HH + k];         break;
      case 3:  v = Wih3[g * 257 + 1 + k];    break;
      case 4:  v = Wih3[g * 257 + 129 + k];  break;
      default: v = Whh3[g * HH + k];         break;
    }
    ws[idx] = v;
  } else if (idx < WLIN) {
    int r = idx - SCAL;
    float v;
    if      (r < 512)  v = Wih1[r];
    else if (r < 1024) v = Wih2[(r - 512) * 129];
    else if (r < 1536) v = Wih3[(r - 1024) * 257];
    else if (r < 2048) v = bih1[r - 1536] + bhh1[r - 1536];
    else if (r < 2560) v = bih2[r - 2048] + bhh2[r - 2048];
    else               v = bih3[r - 2560] + bhh3[r - 2560];
    ws[idx] = v;
  } else if (idx < XT) {
    int j = idx - WLIN;
    ws[idx] = (j < 385) ? Wlin[j] : (j == 385 ? blin[0] : 0.0f);
  } else if (idx < RH1) {
    int j = idx - XT;
    int t = j >> 8, r = j & 255;
    ws[idx] = x[r * TSEQ + t];
  } else if (idx < PREP_TOT) {
    ws[FLAGS + (idx - RH1)] = 0.0f;   // zero flag lines (ws is 0xAA-poisoned)
  }
}

// ---------------------------------------------------------------------------
// k-loop: acc[a] += sum_k w[k] * hbuf[a][k].
// Distributed LDS read (lane l -> h[a][64b+l]) + v_readlane->SGPR + SGPR-fmac.
// Fully unrolled (w[] is a VGPR array: constant indices required).
// Summation order: k ascending per row — identical to R7's dot128.
__device__ __forceinline__ void dot128(const float* __restrict__ w,
                                       const float* __restrict__ hbuf,
                                       float acc[8], int lane) {
  #pragma unroll
  for (int b = 0; b < 2; ++b) {
    float hv[8];
    #pragma unroll
    for (int a = 0; a < 8; ++a) hv[a] = hbuf[a * HH + b * 64 + lane];
    #pragma unroll
    for (int k = 0; k < 64; ++k) {
      #pragma unroll
      for (int a = 0; a < 8; ++a) {
        const float hs = __builtin_bit_cast(float,
            __builtin_amdgcn_readlane(__builtin_bit_cast(int, hv[a]), k));
        acc[a] = fmaf(hs, w[b * 64 + k], acc[a]);
      }
    }
  }
}

// ---------------------------------------------------------------------------
// Core stage: gates = [partials or x-term] + Whh*h_own; activation; publish h.
template <int SSELF, int SWA, int SWB, int NP, int XF, int PB, int PR1, int PR2, int DRH64>
__device__ void core_stage(float* __restrict__ wsm, char* SB, int g) {
  const int tid = threadIdx.x;
  const int lane = tid & 63;
  const int r0 = g * 8;
  float* gs   = (float*)SB;                 // [8][512]
  float* hown = (float*)(SB + 16384);       // [8][128]
  float* xs   = (float*)(SB + 20480);       // [8]

  u64* ws64 = (u64*)wsm;
  unsigned* flagb = (unsigned*)wsm + FLAGS;
  unsigned* Fself = flagb + (size_t)(SSELF * 32 + g) * 32;
  unsigned* Fh    = flagb + (size_t)(6 * 32 + g) * 32;
  unsigned ca = 0, cb = 0, ch = 0;

  float w[128];
  #pragma unroll
  for (int k = 0; k < 128; ++k)
    w[k] = wsm[(size_t)PB * 65536 + (size_t)k * 512 + tid];
  const float xwv = XF ? wsm[SCAL + tid] : 0.f;
  const float bsv = XF ? wsm[SCAL + 1536 + tid] : 0.f;

  for (int i = tid; i < 1024; i += 512) hown[i] = 0.f;
  float cst0 = 0.f, cst1 = 0.f;
  __syncthreads();

  for (int t = 0; t < TT; ++t) {
    if (tid == 0) {
      if constexpr (SWA >= 0)
        wait_c(flagb + (size_t)(SWA * 32 + g) * 32, (unsigned)(t + 1), ca);
      if constexpr (SWB >= 0)
        wait_c(flagb + (size_t)(SWB * 32 + g) * 32, (unsigned)(t + 1), cb);
      unsigned ht = (t >= 15) ? (unsigned)(t - 14) : 0u;
      if (XF && t >= TSEQ && (unsigned)t > ht) ht = (unsigned)t;
      if (ht) wait_c(Fh, ht, ch);
    }
    __syncthreads();
    const int slot = t & 15;

    if (XF) {
      if (tid < 8) {
        float xv;
        if (t < TSEQ) {
          xv = wsm[XT + (size_t)t * 256 + r0 + tid];
        } else {
          unsigned u = __hip_atomic_load(
              (unsigned*)wsm + RO + (size_t)((t - 1) & 15) * 256 + r0 + tid,
              __ATOMIC_RELAXED, __HIP_MEMORY_SCOPE_AGENT);
          xv = __builtin_bit_cast(float, u);
        }
        xs[tid] = xv;
      }
      __syncthreads();
    }

    float acc[8];
    if constexpr (NP == 0) {
      #pragma unroll
      for (int a = 0; a < 8; ++a) acc[a] = fmaf(xwv, xs[a], bsv);
    } else {
      #pragma unroll
      for (int a = 0; a < 8; ++a) {
        unsigned u = __hip_atomic_load(
            (unsigned*)wsm + PR1 + (size_t)(t & 7) * 131072 + (size_t)(r0 + a) * 512 + tid,
            __ATOMIC_RELAXED, __HIP_MEMORY_SCOPE_AGENT);
        acc[a] = __builtin_bit_cast(float, u);
      }
      if constexpr (NP == 2) {
        #pragma unroll
        for (int a = 0; a < 8; ++a) {
          unsigned u = __hip_atomic_load(
              (unsigned*)wsm + PR2 + (size_t)(t & 7) * 131072 + (size_t)(r0 + a) * 512 + tid,
              __ATOMIC_RELAXED, __HIP_MEMORY_SCOPE_AGENT);
          acc[a] += __builtin_bit_cast(float, u);
        }
      }
    }

    dot128(w, hown, acc, lane);

    #pragma unroll
    for (int a = 0; a < 8; ++a) gs[a * 512 + tid] = acc[a];
    __syncthreads();

    // activation: 1024 units / 512 thr = 2 each
    {
      const int row0 = tid >> 7, u0 = tid & 127;
      const float gi = gs[row0 * 512 + u0];
      const float gf = gs[row0 * 512 + 128 + u0];
      const float gg = gs[row0 * 512 + 256 + u0];
      const float go = gs[row0 * 512 + 384 + u0];
      const float c0 = sigmoidf_(gf) * cst0 + sigmoidf_(gi) * tanhf(gg);
      cst0 = c0;
      hown[row0 * HH + u0] = sigmoidf_(go) * tanhf(c0);

      const int i1 = tid + 512;
      const int row1 = i1 >> 7, u1 = i1 & 127;
      const float hi = gs[row1 * 512 + u1];
      const float hf = gs[row1 * 512 + 128 + u1];
      const float hg = gs[row1 * 512 + 256 + u1];
      const float ho = gs[row1 * 512 + 384 + u1];
      const float c1v = sigmoidf_(hf) * cst1 + sigmoidf_(hi) * tanhf(hg);
      cst1 = c1v;
      hown[row1 * HH + u1] = sigmoidf_(ho) * tanhf(c1v);
    }
    __syncthreads();

    // publish h(t): 512 u64 pairs
    {
      const int a = tid >> 6, up = tid & 63;
      u64 v = *(const u64*)&hown[a * HH + up * 2];
      __hip_atomic_store(
          ws64 + DRH64 + (size_t)slot * 16384 + (size_t)(r0 + a) * 64 + up, v,
          __ATOMIC_RELAXED, __HIP_MEMORY_SCOPE_AGENT);
    }
    __syncthreads();                 // vmcnt drained at barrier
    if (tid == 0)
      __hip_atomic_fetch_add(Fself, 1u, __ATOMIC_RELAXED, __HIP_MEMORY_SCOPE_AGENT);
  }
}

// ---------------------------------------------------------------------------
// Helper stage: partial = [x-term+bias if XF] + Wpart * h_src(t); publish.
template <int SSELF, int SW, int XF, int PB, int SI, int SRH64, int DRP>
__device__ void helper_stage(float* __restrict__ wsm, char* SB, int g) {
  const int tid = threadIdx.x;
  const int lane = tid & 63;
  const int r0 = g * 8;
  float* hin = (float*)SB;                  // [8][128]
  float* xs  = (float*)(SB + 4096);         // [8]

  u64* ws64 = (u64*)wsm;
  unsigned* flagb = (unsigned*)wsm + FLAGS;
  unsigned* Fself = flagb + (size_t)(SSELF * 32 + g) * 32;
  unsigned* Fw    = flagb + (size_t)(SW * 32 + g) * 32;
  unsigned* Fh    = flagb + (size_t)(6 * 32 + g) * 32;
  unsigned cw = 0, ch = 0;

  float w[128];
  #pragma unroll
  for (int k = 0; k < 128; ++k)
    w[k] = wsm[(size_t)PB * 65536 + (size_t)k * 512 + tid];
  const float xwv = XF ? wsm[SCAL + SI * 512 + tid] : 0.f;
  const float bsv = XF ? wsm[SCAL + 1536 + SI * 512 + tid] : 0.f;
  __syncthreads();

  for (int t = 0; t < TT; ++t) {
    if (tid == 0) {
      wait_c(Fw, (unsigned)(t + 1), cw);
      unsigned ht = (t >= 7) ? (unsigned)(t - 6) : 0u;
      if (XF && t >= TSEQ && (unsigned)t > ht) ht = (unsigned)t;
      if (ht) wait_c(Fh, ht, ch);
    }
    __syncthreads();
    const int slot = t & 15;

    if (XF) {
      if (tid < 8) {
        float xv;
        if (t < TSEQ) {
          xv = wsm[XT + (size_t)t * 256 + r0 + tid];
        } else {
          unsigned u = __hip_atomic_load(
              (unsigned*)wsm + RO + (size_t)((t - 1) & 15) * 256 + r0 + tid,
              __ATOMIC_RELAXED, __HIP_MEMORY_SCOPE_AGENT);
          xv = __builtin_bit_cast(float, u);
        }
        xs[tid] = xv;
      }
    }
    // stage h_src(t)
    {
      const int a = tid >> 6, up = tid & 63;
      u64 v = __hip_atomic_load(
          ws64 + SRH64 + (size_t)slot * 16384 + (size_t)(r0 + a) * 64 + up,
          __ATOMIC_RELAXED, __HIP_MEMORY_SCOPE_AGENT);
      *(u64*)&hin[a * HH + up * 2] = v;
    }
    __syncthreads();

    float acc[8];
    #pragma unroll
    for (int a = 0; a < 8; ++a) acc[a] = XF ? fmaf(xwv, xs[a], bsv) : 0.f;

    dot128(w, hin, acc, lane);

    #pragma unroll
    for (int a = 0; a < 8; ++a)
      __hip_atomic_store(
          (unsigned*)wsm + DRP + (size_t)(t & 7) * 131072 + (size_t)(r0 + a) * 512 + tid,
          __builtin_bit_cast(unsigned, acc[a]),
          __ATOMIC_RELAXED, __HIP_MEMORY_SCOPE_AGENT);
    __syncthreads();                 // vmcnt drained
    if (tid == 0)
      __hip_atomic_fetch_add(Fself, 1u, __ATOMIC_RELAXED, __HIP_MEMORY_SCOPE_AGENT);
  }
}

// ---------------------------------------------------------------------------
__device__ void head_stage(float* __restrict__ wsm, char* SB, int g,
                           float* __restrict__ out) {
  const int tid = threadIdx.x;
  const int r0 = g * 8;
  float* wl   = (float*)SB;                 // [512]
  float* hin  = (float*)(SB + 2048);        // [3][8][128]
  float* obuf = (float*)(SB + 14336);       // [8][32]
  float* xv   = (float*)(SB + 15360);       // [8]

  u64* ws64 = (u64*)wsm;
  unsigned* flagb = (unsigned*)wsm + FLAGS;
  unsigned* Fself = flagb + (size_t)(6 * 32 + g) * 32;
  unsigned* Fc3   = flagb + (size_t)(5 * 32 + g) * 32;
  unsigned c3c = 0;

  wl[tid] = wsm[WLIN + tid];
  if (tid < 8) xv[tid] = wsm[XT + r0 + tid];
  __syncthreads();

  const int row = tid >> 6, lane = tid & 63;

  for (int t = 0; t < TT; ++t) {
    if (tid == 0) wait_c(Fc3, (unsigned)(t + 1), c3c);
    __syncthreads();
    const int slot = t & 15;

    for (int i = tid; i < 1536; i += 512) {
      const int s = i >> 9, rem = i & 511;
      const int a = rem >> 6, up = rem & 63;
      const size_t base = (s == 0) ? (size_t)RH1_64 : (s == 1) ? (size_t)RH2_64 : (size_t)RH3_64;
      u64 v = __hip_atomic_load(
          ws64 + base + (size_t)slot * 16384 + (size_t)(r0 + a) * 64 + up,
          __ATOMIC_RELAXED, __HIP_MEMORY_SCOPE_AGENT);
      *(u64*)&hin[(s * 8 + a) * HH + up * 2] = v;
    }
    __syncthreads();

    float s = 0.f;
    #pragma unroll
    for (int q = 0; q < 6; ++q) {
      const int j = lane + 64 * q;          // 0..383
      const int si = j >> 7, u = j & 127;
      s = fmaf(wl[1 + j], hin[(si * 8 + row) * HH + u], s);
    }
    #pragma unroll
    for (int off = 32; off > 0; off >>= 1) s += __shfl_down(s, off, 64);
    if (lane == 0) {
      const float o = s + fmaf(wl[0], xv[row], wl[385]);
      obuf[row * 32 + (t & 31)] = o;
      __hip_atomic_store((unsigned*)wsm + RO + (size_t)slot * 256 + r0 + row,
                         __builtin_bit_cast(unsigned, o),
                         __ATOMIC_RELAXED, __HIP_MEMORY_SCOPE_AGENT);
      xv[row] = (t + 1 < TSEQ) ? wsm[XT + (size_t)(t + 1) * 256 + r0 + row] : o;
    }
    __syncthreads();                 // drain o-store + obuf
    if (tid == 0)
      __hip_atomic_fetch_add(Fself, 1u, __ATOMIC_RELAXED, __HIP_MEMORY_SCOPE_AGENT);

    if ((t & 31) == 31) {
      const int tb = t - 31;
      if (tid < 256) {
        const int a = tid >> 5, m = tid & 31;
        out[(size_t)(r0 + a) * TT + tb + m] = obuf[a * 32 + m];
      }
    }
  }
}

// ---------------------------------------------------------------------------
__global__ __launch_bounds__(512, 2)
void lstm_kernel(float* __restrict__ wsm, float* __restrict__ out) {
  __shared__ __align__(16) char SB[20992];
  const int s = blockIdx.x >> 5, g = blockIdx.x & 31;
  switch (s) {
    case 0: core_stage<0, -1, -1, 0, 1, 0, 0, 0, RH1_64>(wsm, SB, g); break;
    case 1: helper_stage<1, 0, 1, 1, 1, RH1_64, RP2>(wsm, SB, g); break;
    case 2: core_stage<2, 1, -1, 1, 0, 2, RP2, 0, RH2_64>(wsm, SB, g); break;
    case 3: helper_stage<3, 0, 1, 3, 2, RH1_64, RP3A>(wsm, SB, g); break;
    case 4: helper_stage<4, 2, 0, 4, 0, RH2_64, RP3B>(wsm, SB, g); break;
    case 5: core_stage<5, 3, 4, 2, 0, 5, RP3A, RP3B, RH3_64>(wsm, SB, g); break;
    default: head_stage(wsm, SB, g, out); break;
  }
}

// ---------------------------------------------------------------------------
extern "C" void kernel_launch(void* const* d_in, const int* in_sizes, int n_in,
                              void* d_out, int out_size, void* d_ws, size_t ws_size,
                              hipStream_t stream) {
  const float* x    = (const float*)d_in[0];
  const float* Wih1 = (const float*)d_in[1];
  const float* Whh1 = (const float*)d_in[2];
  const float* bih1 = (const float*)d_in[3];
  const float* bhh1 = (const float*)d_in[4];
  const float* Wih2 = (const float*)d_in[5];
  const float* Whh2 = (const float*)d_in[6];
  const float* bih2 = (const float*)d_in[7];
  const float* bhh2 = (const float*)d_in[8];
  const float* Wih3 = (const float*)d_in[9];
  const float* Whh3 = (const float*)d_in[10];
  const float* bih3 = (const float*)d_in[11];
  const float* bhh3 = (const float*)d_in[12];
  const float* Wlin = (const float*)d_in[13];
  const float* blin = (const float*)d_in[14];
  float* ws  = (float*)d_ws;
  float* out = (float*)d_out;

  prep_kernel<<<PREP_TOT / 256, 256, 0, stream>>>(
      x, Wih1, Whh1, bih1, bhh1, Wih2, Whh2, bih2, bhh2,
      Wih3, Whh3, bih3, bhh3, Wlin, blin, ws);
  lstm_kernel<<<224, 512, 0, stream>>>(ws, out);
}